// Round 1
// 212.720 us; speedup vs baseline: 1.0755x; 1.0755x over previous
//
#include <hip/hip_runtime.h>
#include <hip/hip_bf16.h>

#define N_Q 256
#define M_S 1024
#define DD 512
#define HH 512

typedef __attribute__((ext_vector_type(8))) short short8;
typedef __attribute__((ext_vector_type(8))) __bf16 bf16x8;
typedef __attribute__((ext_vector_type(16))) float f32x16;
typedef __attribute__((ext_vector_type(2))) __bf16 bf16x2;

union U8 { short8 s; bf16x8 b; };

__device__ __forceinline__ unsigned short f2bf(float f) {
  unsigned int u = __float_as_uint(f);
  u += 0x7FFFu + ((u >> 16) & 1u);
  return (unsigned short)(u >> 16);
}

__device__ __forceinline__ short8 pack8(const float* d) {
#if defined(__has_builtin) && __has_builtin(__builtin_amdgcn_cvt_pk_bf16_f32)
  short8 r;
#pragma unroll
  for (int i = 0; i < 4; ++i) {
    union { bf16x2 v; short s[2]; } u;
    u.v = __builtin_amdgcn_cvt_pk_bf16_f32(d[2 * i], d[2 * i + 1]);
    r[2 * i] = u.s[0];
    r[2 * i + 1] = u.s[1];
  }
  return r;
#else
  short8 r;
#pragma unroll
  for (int i = 0; i < 8; ++i) r[i] = (short)f2bf(d[i]);
  return r;
#endif
}

__device__ __forceinline__ short8 packdiff(float4 e0, float4 e1, float4 s0, float4 s1) {
  float d[8];
  d[0] = fabsf(e0.x - s0.x); d[1] = fabsf(e0.y - s0.y);
  d[2] = fabsf(e0.z - s0.z); d[3] = fabsf(e0.w - s0.w);
  d[4] = fabsf(e1.x - s1.x); d[5] = fabsf(e1.y - s1.y);
  d[6] = fabsf(e1.z - s1.z); d[7] = fabsf(e1.w - s1.w);
  return pack8(d);
}

// W1 [D][H] fp32 -> w1s in MFMA-fragment order (verified in prior session).
// Frag f = kc*16 + h32; elem (lane l, j) = W1[kc*16 + (l>>5)*8 + j][h32*32 + (l&31)].
// Used as the *A* operand now: A[row=h (l&31)][k=(l>>5)*8+j] = W1^T slice. Same bytes.
__global__ __launch_bounds__(512) void prep_w1s(const float* __restrict__ W1,
                                                unsigned short* __restrict__ w1s) {
  const int f = blockIdx.x;            // 0..511
  const int kc = f >> 4, h32 = f & 15;
  const int l = threadIdx.x & 63, j = threadIdx.x >> 6;
  const int h = h32 * 32 + (l & 31);
  const int k = kc * 16 + (l >> 5) * 8 + j;
  w1s[f * 512 + l * 8 + j] = f2bf(W1[k * HH + h]);
}

// Block: 1024 thr = 16 waves. Tile 128 pairs (8 emb x 16 sup) x 512 h x K=512.
// A (diff) staged ONCE into 128 KB dynamic LDS, layout [p][c ^ (p&7)] in 16B
// chunks. Wave wid: hslice = wid&7 (64 h), pgset = wid>>3 (64 pairs).
// MFMA operand-swapped: A = W1^T frag (registers, from w1s/L2), B = diff frag
// (LDS) -> C col = pair, row = h => epilogue h-reduce is IN-LANE (no butterfly).
// W1 L2 traffic: 2048 blocks x 512 KB = 1.05 GB (was 2.1 GB at 64-pair tiles).
__global__ __launch_bounds__(1024, 4) void support_kernel(
    const float* __restrict__ emb, const float* __restrict__ sup,
    const unsigned short* __restrict__ w1s, const float* __restrict__ b1,
    const float* __restrict__ W2, const float* __restrict__ b2,
    float* __restrict__ out) {
  extern __shared__ short8 As16[];   // [128 pairs][64 chunks], 131072 B

  const int tid = threadIdx.x;
  const int lane = tid & 63;
  const int wid = tid >> 6;          // 0..15
  const int l31 = lane & 31;
  const int khalf = lane >> 5;
  const int hslice = wid & 7;        // h base = hslice*64
  const int pgset = wid >> 3;        // pair base = pgset*64

  const int m0 = blockIdx.x * 16;
  const int n0 = blockIdx.y * 8;

  // ---- staging map: c = 16B k-chunk (0..63), rg = tid>>6 -> 8 rows each ----
  const int c = tid & 63;
  const int rg = tid >> 6;           // 0..15 (wave-uniform)
  const int nl = rg >> 1;            // emb row 0..7
  const int mq = rg & 1;             // sup half

  // B (=A-operand W1 frags) prologue for ks=0,1 issued BEFORE staging
  const unsigned short* bb = w1s + (hslice * 2) * 512 + lane * 8;
  U8 b[3][2];
#pragma unroll
  for (int tj = 0; tj < 2; ++tj) {
    b[0][tj].s = *(const short8*)(bb + (0 * 16 + tj) * 512);
    b[1][tj].s = *(const short8*)(bb + (1 * 16 + tj) * 512);
  }

  // ---- stage 128p x 512k diffs (once) ----
  {
    const float* ep = emb + (n0 + nl) * DD + c * 8;
    const float4 e0 = *(const float4*)ep;
    const float4 e1 = *(const float4*)(ep + 4);
    const float* sbase = sup + (m0 + mq * 8) * DD + c * 8;
#pragma unroll
    for (int j = 0; j < 8; ++j) {
      const float4 s0 = *(const float4*)(sbase + j * DD);
      const float4 s1 = *(const float4*)(sbase + j * DD + 4);
      const int p = rg * 8 + j;                 // p&7 == j
      As16[p * 64 + (c ^ j)] = packdiff(e0, e1, s0, s1);
    }
  }
  __syncthreads();  // barrier 1: tile visible

  // ---- barrier-free K-loop: 32 steps of 16 k ----
  const int ar0 = (pgset * 64 + 0 + l31) * 64;    // B-frag row (pair), short8 units
  const int ar1 = (pgset * 64 + 32 + l31) * 64;
  const int ax = l31 & 7;            // read-side chunk XOR (row&7 == l31&7)

  f32x16 acc[2][2] = {};
  U8 a[2][2];
  a[0][0].s = As16[ar0 + (khalf ^ ax)];
  a[0][1].s = As16[ar1 + (khalf ^ ax)];

#pragma unroll
  for (int ks = 0; ks < 32; ++ks) {
    const int cur = ks & 1;
    if (ks < 31) {  // A lookahead depth 1 (LDS)
      const int cc = ((ks + 1) * 2 + khalf) ^ ax;
      a[cur ^ 1][0].s = As16[ar0 + cc];
      a[cur ^ 1][1].s = As16[ar1 + cc];
    }
    if (ks + 2 < 32) {  // W1-frag lookahead depth 2 (L2)
#pragma unroll
      for (int tj = 0; tj < 2; ++tj)
        b[(ks + 2) % 3][tj].s = *(const short8*)(bb + ((ks + 2) * 16 + tj) * 512);
    }
    __builtin_amdgcn_s_setprio(1);
#pragma unroll
    for (int am = 0; am < 2; ++am)
#pragma unroll
      for (int tj = 0; tj < 2; ++tj)
        acc[am][tj] = __builtin_amdgcn_mfma_f32_32x32x16_bf16(
            b[ks % 3][tj].b, a[cur][am].b, acc[am][tj], 0, 0, 0);
    __builtin_amdgcn_s_setprio(0);
  }

  // ---- epilogue: C col = pair (l31), row = h: (r&3)+8*(r>>2)+4*khalf ----
  // In-lane reduce over 64 h per wave; one xor-32 shuffle; psums stride 9.
  float s[2];
#pragma unroll
  for (int am = 0; am < 2; ++am) {
    float sm = 0.f;
#pragma unroll
    for (int tj = 0; tj < 2; ++tj) {
      const float* b1p = b1 + (hslice * 2 + tj) * 32 + khalf * 4;
      const float* w2p = W2 + (hslice * 2 + tj) * 32 + khalf * 4;
#pragma unroll
      for (int rq = 0; rq < 4; ++rq) {
        const float4 b1q = *(const float4*)(b1p + rq * 8);
        const float4 w2q = *(const float4*)(w2p + rq * 8);
        sm += fmaxf(acc[am][tj][rq * 4 + 0] + b1q.x, 0.f) * w2q.x;
        sm += fmaxf(acc[am][tj][rq * 4 + 1] + b1q.y, 0.f) * w2q.y;
        sm += fmaxf(acc[am][tj][rq * 4 + 2] + b1q.z, 0.f) * w2q.z;
        sm += fmaxf(acc[am][tj][rq * 4 + 3] + b1q.w, 0.f) * w2q.w;
      }
    }
    sm += __shfl_xor(sm, 32, 64);  // combine khalf halves (k-rows of C)
    s[am] = sm;
  }
  __syncthreads();  // barrier 2: all As16 reads done before aliasing
  float* psums = (float*)As16;  // [128 pairs][9] (pad -> conflict-free)
  // lane = khalf*32 + l31: khalf 0 writes am=0 row, khalf 1 writes am=1 row
  psums[(pgset * 64 + lane) * 9 + hslice] = khalf ? s[1] : s[0];
  __syncthreads();  // barrier 3
  if (tid < 128) {
    float t = b2[0];
#pragma unroll
    for (int w = 0; w < 8; ++w) t += psums[tid * 9 + w];
    out[(n0 + (tid >> 4)) * M_S + m0 + (tid & 15)] = 1.f / (1.f + __expf(-t));
  }
}

extern "C" void kernel_launch(void* const* d_in, const int* in_sizes, int n_in,
                              void* d_out, int out_size, void* d_ws, size_t ws_size,
                              hipStream_t stream) {
  const float* emb = (const float*)d_in[0];
  const float* sup = (const float*)d_in[1];
  const float* W1  = (const float*)d_in[2];
  const float* b1  = (const float*)d_in[3];
  const float* W2  = (const float*)d_in[4];
  const float* b2  = (const float*)d_in[5];
  float* out = (float*)d_out;
  unsigned short* w1s = (unsigned short*)d_ws;  // 512 KB fragment-ordered W1

  static bool attr_done = false;
  if (!attr_done) {
    hipFuncSetAttribute((const void*)support_kernel,
                        hipFuncAttributeMaxDynamicSharedMemorySize, 131072);
    attr_done = true;
  }

  prep_w1s<<<512, 512, 0, stream>>>(W1, w1s);
  support_kernel<<<dim3(M_S / 16, N_Q / 8), 1024, 131072, stream>>>(
      emb, sup, w1s, b1, W2, b2, out);
}

// Round 3
// 185.741 us; speedup vs baseline: 1.2318x; 1.1453x over previous
//
#include <hip/hip_runtime.h>
#include <hip/hip_bf16.h>

#define N_Q 256
#define M_S 1024
#define DD 512
#define HH 512

typedef __attribute__((ext_vector_type(8))) short short8;
typedef __attribute__((ext_vector_type(8))) __bf16 bf16x8;
typedef __attribute__((ext_vector_type(16))) float f32x16;
typedef __attribute__((ext_vector_type(2))) __bf16 bf16x2;

union U8 { short8 s; bf16x8 b; };

__device__ __forceinline__ unsigned short f2bf(float f) {
  unsigned int u = __float_as_uint(f);
  u += 0x7FFFu + ((u >> 16) & 1u);
  return (unsigned short)(u >> 16);
}

__device__ __forceinline__ short8 pack8(const float* d) {
#if defined(__has_builtin) && __has_builtin(__builtin_amdgcn_cvt_pk_bf16_f32)
  short8 r;
#pragma unroll
  for (int i = 0; i < 4; ++i) {
    union { bf16x2 v; short s[2]; } u;
    u.v = __builtin_amdgcn_cvt_pk_bf16_f32(d[2 * i], d[2 * i + 1]);
    r[2 * i] = u.s[0];
    r[2 * i + 1] = u.s[1];
  }
  return r;
#else
  short8 r;
#pragma unroll
  for (int i = 0; i < 8; ++i) r[i] = (short)f2bf(d[i]);
  return r;
#endif
}

__device__ __forceinline__ short8 packdiff(float4 e0, float4 e1, float4 s0, float4 s1) {
  float d[8];
  d[0] = fabsf(e0.x - s0.x); d[1] = fabsf(e0.y - s0.y);
  d[2] = fabsf(e0.z - s0.z); d[3] = fabsf(e0.w - s0.w);
  d[4] = fabsf(e1.x - s1.x); d[5] = fabsf(e1.y - s1.y);
  d[6] = fabsf(e1.z - s1.z); d[7] = fabsf(e1.w - s1.w);
  return pack8(d);
}

// W1 [D][H] fp32 -> w1s in MFMA-fragment order (verified in prior session).
// Frag f = kc*16 + h32; elem (lane l, j) = W1[kc*16 + (l>>5)*8 + j][h32*32 + (l&31)].
// Used as the A operand: A[row=h (l&31)][k=(l>>5)*8+j] = W1^T slice.
__global__ __launch_bounds__(512) void prep_w1s(const float* __restrict__ W1,
                                                unsigned short* __restrict__ w1s) {
  const int f = blockIdx.x;            // 0..511
  const int kc = f >> 4, h32 = f & 15;
  const int l = threadIdx.x & 63, j = threadIdx.x >> 6;
  const int h = h32 * 32 + (l & 31);
  const int k = kc * 16 + (l >> 5) * 8 + j;
  w1s[f * 512 + l * 8 + j] = f2bf(W1[k * HH + h]);
}

// Block: 512 thr = 8 waves. Tile 128 pairs (8 emb x 16 sup) x 512 h x K=512.
// A (diff) staged ONCE into 128 KB dynamic LDS, layout [p][c ^ (p&7)] in 16B
// chunks. Wave wid = hslice (64 h each); EVERY wave covers all 128 pairs
// (acc[4][2] = 128 AGPR). MFMA operand-swapped: A = W1^T frag (regs, L2),
// B = diff frag (LDS) -> C col = pair, row = h => in-lane h-reduce epilogue.
// W1 L2 traffic: w1s streamed ONCE per block = 2048 x 512 KB = 1.05 GB.
// W1 demand 31.7 B/cyc/CU < 56 share; LDS demand 63.5 B/cyc < 128.
// MFMA (16.5 K cyc/block) is the critical pipe.
// ~205 VGPR -> 2 waves/SIMD, 1 block/CU (128 KB LDS).
__global__ __launch_bounds__(512, 2) void support_kernel(
    const float* __restrict__ emb, const float* __restrict__ sup,
    const unsigned short* __restrict__ w1s, const float* __restrict__ b1,
    const float* __restrict__ W2, const float* __restrict__ b2,
    float* __restrict__ out) {
  extern __shared__ short8 As16[];   // [128 pairs][64 chunks], 131072 B

  const int tid = threadIdx.x;
  const int lane = tid & 63;
  const int wid = tid >> 6;          // 0..7 = hslice (h base = wid*64)
  const int l31 = lane & 31;
  const int khalf = lane >> 5;

  const int m0 = blockIdx.x * 16;
  const int n0 = blockIdx.y * 8;

  // ---- W1-frag (A-operand) prologue for ks=0,1 issued BEFORE staging ----
  const unsigned short* bb = w1s + (wid * 2) * 512 + lane * 8;
  U8 b[3][2];
#pragma unroll
  for (int tj = 0; tj < 2; ++tj) {
    b[0][tj].s = *(const short8*)(bb + (0 * 16 + tj) * 512);
    b[1][tj].s = *(const short8*)(bb + (1 * 16 + tj) * 512);
  }

  // ---- stage 128p x 512k diffs (once): thread = (emb row rg, k-chunk c) ----
  {
    const int c = tid & 63;
    const int rg = tid >> 6;           // emb row 0..7
    const float* ep = emb + (n0 + rg) * DD + c * 8;
    const float4 e0 = *(const float4*)ep;
    const float4 e1 = *(const float4*)(ep + 4);
    const float* sbase = sup + m0 * DD + c * 8;
#pragma unroll
    for (int j = 0; j < 16; ++j) {     // 16 sup rows
      const float4 s0 = *(const float4*)(sbase + j * DD);
      const float4 s1 = *(const float4*)(sbase + j * DD + 4);
      const int p = rg * 16 + j;       // p&7 == j&7
      As16[p * 64 + (c ^ (j & 7))] = packdiff(e0, e1, s0, s1);
    }
  }
  __syncthreads();  // barrier 1: tile visible

  // ---- barrier-free K-loop: 32 steps of 16 k, 8 MFMA each ----
  const int ax = l31 & 7;            // read-side chunk XOR (row&7 == l31&7)
  const int ar0 = (0 * 32 + l31) * 64;
  const int ar1 = (1 * 32 + l31) * 64;
  const int ar2 = (2 * 32 + l31) * 64;
  const int ar3 = (3 * 32 + l31) * 64;

  f32x16 acc[4][2] = {};
  U8 a[2][4];
  {
    const int c0 = khalf ^ ax;
    a[0][0].s = As16[ar0 + c0];
    a[0][1].s = As16[ar1 + c0];
    a[0][2].s = As16[ar2 + c0];
    a[0][3].s = As16[ar3 + c0];
  }

#pragma unroll
  for (int ks = 0; ks < 32; ++ks) {
    const int cur = ks & 1;
    if (ks < 31) {  // diff-frag lookahead depth 1 (LDS)
      const int cc = ((ks + 1) * 2 + khalf) ^ ax;
      a[cur ^ 1][0].s = As16[ar0 + cc];
      a[cur ^ 1][1].s = As16[ar1 + cc];
      a[cur ^ 1][2].s = As16[ar2 + cc];
      a[cur ^ 1][3].s = As16[ar3 + cc];
    }
    if (ks + 2 < 32) {  // W1-frag lookahead depth 2 (L2)
#pragma unroll
      for (int tj = 0; tj < 2; ++tj)
        b[(ks + 2) % 3][tj].s = *(const short8*)(bb + ((ks + 2) * 16 + tj) * 512);
    }
    __builtin_amdgcn_s_setprio(1);
#pragma unroll
    for (int am = 0; am < 4; ++am)
#pragma unroll
      for (int tj = 0; tj < 2; ++tj)
        acc[am][tj] = __builtin_amdgcn_mfma_f32_32x32x16_bf16(
            b[ks % 3][tj].b, a[cur][am].b, acc[am][tj], 0, 0, 0);
    __builtin_amdgcn_s_setprio(0);
  }

  // ---- epilogue: C col = pair (l31 + am*32), row = h: (r&3)+8*(r>>2)+4*khalf
  // In-lane reduce over 64 h per wave; one xor-32 shuffle per am.
  float s0a, s1a, s2a, s3a;
  {
    float sm[4] = {0.f, 0.f, 0.f, 0.f};
#pragma unroll
    for (int tj = 0; tj < 2; ++tj) {
      const float* b1p = b1 + (wid * 2 + tj) * 32 + khalf * 4;
      const float* w2p = W2 + (wid * 2 + tj) * 32 + khalf * 4;
#pragma unroll
      for (int rq = 0; rq < 4; ++rq) {
        const float4 b1q = *(const float4*)(b1p + rq * 8);
        const float4 w2q = *(const float4*)(w2p + rq * 8);
#pragma unroll
        for (int am = 0; am < 4; ++am) {
          sm[am] += fmaxf(acc[am][tj][rq * 4 + 0] + b1q.x, 0.f) * w2q.x;
          sm[am] += fmaxf(acc[am][tj][rq * 4 + 1] + b1q.y, 0.f) * w2q.y;
          sm[am] += fmaxf(acc[am][tj][rq * 4 + 2] + b1q.z, 0.f) * w2q.z;
          sm[am] += fmaxf(acc[am][tj][rq * 4 + 3] + b1q.w, 0.f) * w2q.w;
        }
      }
    }
#pragma unroll
    for (int am = 0; am < 4; ++am) sm[am] += __shfl_xor(sm[am], 32, 64);
    s0a = sm[0]; s1a = sm[1]; s2a = sm[2]; s3a = sm[3];
  }
  __syncthreads();  // barrier 2: all As16 reads done before aliasing
  float* psums = (float*)As16;  // [128 pairs][9] (pad 9 -> conflict-free)
  // khalf 0 writes am 0,1; khalf 1 writes am 2,3 (all lanes hold full sums)
  {
    const float v0 = khalf ? s2a : s0a;
    const float v1 = khalf ? s3a : s1a;
    const int p0 = khalf * 64 + l31;       // am = khalf*2     -> pair base
    psums[p0 * 9 + wid] = v0;
    psums[(p0 + 32) * 9 + wid] = v1;       // am = khalf*2 + 1
  }
  __syncthreads();  // barrier 3
  if (tid < 128) {
    float t = b2[0];
#pragma unroll
    for (int w = 0; w < 8; ++w) t += psums[tid * 9 + w];
    out[(n0 + (tid >> 4)) * M_S + m0 + (tid & 15)] = 1.f / (1.f + __expf(-t));
  }
}

extern "C" void kernel_launch(void* const* d_in, const int* in_sizes, int n_in,
                              void* d_out, int out_size, void* d_ws, size_t ws_size,
                              hipStream_t stream) {
  const float* emb = (const float*)d_in[0];
  const float* sup = (const float*)d_in[1];
  const float* W1  = (const float*)d_in[2];
  const float* b1  = (const float*)d_in[3];
  const float* W2  = (const float*)d_in[4];
  const float* b2  = (const float*)d_in[5];
  float* out = (float*)d_out;
  unsigned short* w1s = (unsigned short*)d_ws;  // 512 KB fragment-ordered W1

  static bool attr_done = false;
  if (!attr_done) {
    hipFuncSetAttribute((const void*)support_kernel,
                        hipFuncAttributeMaxDynamicSharedMemorySize, 131072);
    attr_done = true;
  }

  prep_w1s<<<512, 512, 0, stream>>>(W1, w1s);
  support_kernel<<<dim3(M_S / 16, N_Q / 8), 512, 131072, stream>>>(
      emb, sup, w1s, b1, W2, b2, out);
}